// Round 5
// baseline (92.448 us; speedup 1.0000x reference)
//
#include <hip/hip_runtime.h>
#include <hip/hip_cooperative_groups.h>

namespace cg = cooperative_groups;

#define CW 48
#define HR 3
#define VR 3
#define BB 2
#define CC 16
#define HH 128
#define WW 256

#define LW 312      // Lsh stride: idx = x+3; max read idx 308 (w=255,d=47,dx=3)
#define RW2 264     // Rsh stride: idx = x+3, valid data 3..258
#define SW 264      // Ssh stride: xi 0..261 used
#define FWD (WW*CW) // 12288 floats per (b,h) plane
#define HSEG 16

// One cooperative kernel. Block (b,y): phase A computes Hws[b][y][w][d]
// (horizontal 7-tap of ssd_raw row y); grid sync; phase B does the vertical
// 7-tap running sum over Hws and writes out.
__global__ __launch_bounds__(256) void ssd_fused(
    const float* __restrict__ Lg, const float* __restrict__ Rg,
    float* __restrict__ Hws, float* __restrict__ out)
{
    const int bid = blockIdx.x;     // 0..255
    const int y   = bid % HH;
    const int b   = bid / HH;
    const int tid = threadIdx.x;

    __shared__ float Lsh[CC * LW];
    __shared__ float Rsh[CC * RW2];
    __shared__ float Ssh[CW * SW];
    __shared__ float el[LW];
    __shared__ float er[RW2];

    // ---------------- phase A ----------------
    // zero only the pad regions (valid cols overwritten below)
    for (int i = tid; i < CC * 56; i += 256) {      // Lsh idx 0..2, 259..311
        int c = i / 56, j = i % 56;
        int idx = (j < 3) ? j : (256 + j);
        Lsh[c * LW + idx] = 0.f;
    }
    for (int i = tid; i < CC * 8; i += 256) {       // Rsh idx 0..2, 259..263
        int c = i >> 3, j = i & 7;
        int idx = (j < 3) ? j : (256 + j);
        Rsh[c * RW2 + idx] = 0.f;
    }

    // stage one image row (16 channels), coalesced
    const size_t ib = ((size_t)b * CC) * (HH * WW) + (size_t)y * WW + tid;
    #pragma unroll
    for (int c = 0; c < CC; ++c) {
        Lsh[c * LW  + HR + tid] = Lg[ib + (size_t)c * (HH * WW)];
        Rsh[c * RW2 + HR + tid] = Rg[ib + (size_t)c * (HH * WW)];
    }
    __syncthreads();

    // el(idx) = sum_c L^2, er(idx) = sum_c R^2 (pads already zero)
    for (int i = tid; i < LW; i += 256) {
        float s = 0.f;
        #pragma unroll
        for (int c = 0; c < CC; ++c) { float v = Lsh[c * LW + i]; s = fmaf(v, v, s); }
        el[i] = s;
    }
    for (int i = tid; i < RW2; i += 256) {
        float s = 0.f;
        #pragma unroll
        for (int c = 0; c < CC; ++c) { float v = Rsh[c * RW2 + i]; s = fmaf(v, v, s); }
        er[i] = s;
    }
    __syncthreads();

    // main cc: exactly one unit per thread (q = d-quarter, 4 consecutive xi)
    {
        const int q   = tid >> 6;            // d0 = 12q
        const int xi0 = (tid & 63) * 4;      // 0..252
        const int d0  = q * 12;

        float acc[12][4];
        #pragma unroll
        for (int dd = 0; dd < 12; ++dd)
            #pragma unroll
            for (int xv = 0; xv < 4; ++xv) acc[dd][xv] = 0.f;

        #pragma unroll
        for (int c = 0; c < CC; ++c) {
            const float4 rv = *(const float4*)&Rsh[c * RW2 + xi0];
            const float rr[4] = {rv.x, rv.y, rv.z, rv.w};
            float lv[16];
            #pragma unroll
            for (int k = 0; k < 4; ++k)
                *(float4*)&lv[4 * k] = *(const float4*)&Lsh[c * LW + xi0 + d0 + 4 * k];
            #pragma unroll
            for (int dd = 0; dd < 12; ++dd)
                #pragma unroll
                for (int xv = 0; xv < 4; ++xv)
                    acc[dd][xv] = fmaf(lv[dd + xv], rr[xv], acc[dd][xv]);
        }

        float elv[16];
        #pragma unroll
        for (int k = 0; k < 4; ++k)
            *(float4*)&elv[4 * k] = *(const float4*)&el[xi0 + d0 + 4 * k];
        const float4 e4 = *(const float4*)&er[xi0];
        const float err4[4] = {e4.x, e4.y, e4.z, e4.w};
        #pragma unroll
        for (int dd = 0; dd < 12; ++dd) {
            float4 o;
            o.x = elv[dd + 0] + err4[0] - 2.f * acc[dd][0];
            o.y = elv[dd + 1] + err4[1] - 2.f * acc[dd][1];
            o.z = elv[dd + 2] + err4[2] - 2.f * acc[dd][2];
            o.w = elv[dd + 3] + err4[3] - 2.f * acc[dd][3];
            *(float4*)&Ssh[(d0 + dd) * SW + xi0] = o;
        }
    }
    // leftover xi 256..261 (6 xi x 48 d = 288 scalar units)
    for (int p = tid; p < 6 * CW; p += 256) {
        int dd = p % CW;
        int xi = 256 + p / CW;
        float a = 0.f;
        #pragma unroll
        for (int c = 0; c < CC; ++c)
            a = fmaf(Lsh[c * LW + xi + dd], Rsh[c * RW2 + xi], a);
        Ssh[dd * SW + xi] = el[xi + dd] + er[xi] - 2.f * a;
    }
    __syncthreads();

    // horizontal 7-tap + d-contiguous store to Hws[b][y][w][d]
    {
        const int q  = tid >> 6;
        const int w0 = (tid & 63) * 4;
        const int d0 = q * 12;
        float hs[12][4];
        #pragma unroll
        for (int dd = 0; dd < 12; ++dd) {
            const float* row = &Ssh[(d0 + dd) * SW];
            const float4 a  = *(const float4*)&row[w0];
            const float4 bv = *(const float4*)&row[w0 + 4];
            const float2 cv = *(const float2*)&row[w0 + 8];
            float p = a.x + a.y + a.z + a.w + bv.x + bv.y + bv.z;
            hs[dd][0] = p;
            p += bv.w - a.x; hs[dd][1] = p;
            p += cv.x - a.y; hs[dd][2] = p;
            p += cv.y - a.z; hs[dd][3] = p;
        }
        float* H = Hws + (size_t)(b * HH + y) * FWD;
        #pragma unroll
        for (int xv = 0; xv < 4; ++xv) {
            float4 v0 = {hs[0][xv], hs[1][xv], hs[2][xv],  hs[3][xv]};
            float4 v1 = {hs[4][xv], hs[5][xv], hs[6][xv],  hs[7][xv]};
            float4 v2 = {hs[8][xv], hs[9][xv], hs[10][xv], hs[11][xv]};
            float* p = &H[(w0 + xv) * CW + d0];
            *(float4*)&p[0] = v0;
            *(float4*)&p[4] = v1;
            *(float4*)&p[8] = v2;
        }
    }

    cg::this_grid().sync();

    // ---------------- phase B: vertical 7-tap running sum ----------------
    #pragma unroll
    for (int s = 0; s < 3; ++s) {
        const int unit = bid * 3 + s;              // 0..767
        const int fb = unit % CW;
        const int hs = (unit / CW) % (HH / HSEG);
        const int bb = unit / (CW * (HH / HSEG));
        const int f  = fb * 256 + tid;             // f = w*48 + d
        const int h0 = hs * HSEG;

        const float* H = Hws + (size_t)bb * HH * FWD + f;
        float*       O = out + (size_t)bb * HH * FWD + f;

        float ssum = 0.f;
        #pragma unroll
        for (int k = 0; k < 6; ++k) {              // yy = h0-3 .. h0+2
            int yy = h0 - 3 + k;
            if (yy >= 0) ssum += H[(size_t)yy * FWD];
        }
        #pragma unroll
        for (int hi = 0; hi < HSEG; ++hi) {
            int h = h0 + hi;
            if (h + 3 < HH) ssum += H[(size_t)(h + 3) * FWD];
            O[(size_t)h * FWD] = ssum;
            if (h - 3 >= 0) ssum -= H[(size_t)(h - 3) * FWD];
        }
    }
}

extern "C" void kernel_launch(void* const* d_in, const int* in_sizes, int n_in,
                              void* d_out, int out_size, void* d_ws, size_t ws_size,
                              hipStream_t stream) {
    const float* L = (const float*)d_in[0];
    const float* R = (const float*)d_in[1];
    float* outp = (float*)d_out;
    float* Hws  = (float*)d_ws;   // BB*HH*WW*CW*4 = 12.6 MB

    void* args[] = {(void*)&L, (void*)&R, (void*)&Hws, (void*)&outp};
    hipLaunchCooperativeKernel((const void*)ssd_fused, dim3(BB * HH), dim3(256),
                               args, 0, stream);
}

// Round 6
// 29.688 us; speedup vs baseline: 3.1140x; 3.1140x over previous
//
#include <hip/hip_runtime.h>

#define CW 48
#define HR 3
#define VR 3
#define BB 2
#define CC 16
#define HH 128
#define WW 256

#define LW 312      // Lsh stride: idx = x+3; max read idx 308 (w=255,d=47,dx=3)
#define RW2 264     // Rsh stride: idx = x+3, valid data 3..258
#define SW 264      // Ssh stride: xi 0..261 used
#define FWD (WW*CW) // 12288 floats per (b,h) plane
#define HSEG 16

// ------------- Kernel A: one block per (b,y) row; all 48 disparities -------------
// Hws[b][y][w][d] = horizontal 7-tap of ssd_raw(y, x, d), via ssd = el+er-2cc
__global__ __launch_bounds__(256) void ssd_hraw(
    const float* __restrict__ Lg, const float* __restrict__ Rg,
    float* __restrict__ Hws)
{
    const int bid = blockIdx.x;     // 0..255
    const int y   = bid % HH;
    const int b   = bid / HH;
    const int tid = threadIdx.x;

    __shared__ float Lsh[CC * LW];
    __shared__ float Rsh[CC * RW2];
    __shared__ float Ssh[CW * SW];
    __shared__ float el[LW];
    __shared__ float er[RW2];

    // zero only pad regions (valid cols overwritten below)
    for (int i = tid; i < CC * 56; i += 256) {      // Lsh idx 0..2, 259..311
        int c = i / 56, j = i % 56;
        int idx = (j < 3) ? j : (256 + j);
        Lsh[c * LW + idx] = 0.f;
    }
    for (int i = tid; i < CC * 8; i += 256) {       // Rsh idx 0..2, 259..263
        int c = i >> 3, j = i & 7;
        int idx = (j < 3) ? j : (256 + j);
        Rsh[c * RW2 + idx] = 0.f;
    }

    // stage one image row (16 channels), coalesced
    const size_t ib = ((size_t)b * CC) * (HH * WW) + (size_t)y * WW + tid;
    #pragma unroll
    for (int c = 0; c < CC; ++c) {
        Lsh[c * LW  + HR + tid] = Lg[ib + (size_t)c * (HH * WW)];
        Rsh[c * RW2 + HR + tid] = Rg[ib + (size_t)c * (HH * WW)];
    }
    __syncthreads();

    // el(idx) = sum_c L^2, er(idx) = sum_c R^2 — one fused loop (balanced tail)
    for (int i = tid; i < LW + RW2; i += 256) {
        if (i < LW) {
            float s = 0.f;
            #pragma unroll
            for (int c = 0; c < CC; ++c) { float v = Lsh[c * LW + i]; s = fmaf(v, v, s); }
            el[i] = s;
        } else {
            int j = i - LW;
            float s = 0.f;
            #pragma unroll
            for (int c = 0; c < CC; ++c) { float v = Rsh[c * RW2 + j]; s = fmaf(v, v, s); }
            er[j] = s;
        }
    }
    __syncthreads();

    // main cc: exactly ONE unit per thread (q = d-quarter, 4 consecutive xi)
    {
        const int q   = tid >> 6;            // d0 = 12q
        const int xi0 = (tid & 63) * 4;      // 0..252
        const int d0  = q * 12;

        float acc[12][4];
        #pragma unroll
        for (int dd = 0; dd < 12; ++dd)
            #pragma unroll
            for (int xv = 0; xv < 4; ++xv) acc[dd][xv] = 0.f;

        #pragma unroll
        for (int c = 0; c < CC; ++c) {
            const float4 rv = *(const float4*)&Rsh[c * RW2 + xi0];
            const float rr[4] = {rv.x, rv.y, rv.z, rv.w};
            float lv[16];
            #pragma unroll
            for (int k = 0; k < 4; ++k)
                *(float4*)&lv[4 * k] = *(const float4*)&Lsh[c * LW + xi0 + d0 + 4 * k];
            #pragma unroll
            for (int dd = 0; dd < 12; ++dd)
                #pragma unroll
                for (int xv = 0; xv < 4; ++xv)
                    acc[dd][xv] = fmaf(lv[dd + xv], rr[xv], acc[dd][xv]);
        }

        float elv[16];
        #pragma unroll
        for (int k = 0; k < 4; ++k)
            *(float4*)&elv[4 * k] = *(const float4*)&el[xi0 + d0 + 4 * k];
        const float4 e4 = *(const float4*)&er[xi0];
        const float err4[4] = {e4.x, e4.y, e4.z, e4.w};
        #pragma unroll
        for (int dd = 0; dd < 12; ++dd) {
            float4 o;
            o.x = elv[dd + 0] + err4[0] - 2.f * acc[dd][0];
            o.y = elv[dd + 1] + err4[1] - 2.f * acc[dd][1];
            o.z = elv[dd + 2] + err4[2] - 2.f * acc[dd][2];
            o.w = elv[dd + 3] + err4[3] - 2.f * acc[dd][3];
            *(float4*)&Ssh[(d0 + dd) * SW + xi0] = o;
        }
    }
    // leftover xi 256..261 (6 xi x 48 d = 288 small scalar units)
    for (int p = tid; p < 6 * CW; p += 256) {
        int dd = p % CW;
        int xi = 256 + p / CW;
        float a = 0.f;
        #pragma unroll
        for (int c = 0; c < CC; ++c)
            a = fmaf(Lsh[c * LW + xi + dd], Rsh[c * RW2 + xi], a);
        Ssh[dd * SW + xi] = el[xi + dd] + er[xi] - 2.f * a;
    }
    __syncthreads();

    // horizontal 7-tap + d-contiguous store to Hws[b][y][w][d]
    {
        const int q  = tid >> 6;
        const int w0 = (tid & 63) * 4;
        const int d0 = q * 12;
        float hs[12][4];
        #pragma unroll
        for (int dd = 0; dd < 12; ++dd) {
            const float* row = &Ssh[(d0 + dd) * SW];
            const float4 a  = *(const float4*)&row[w0];
            const float4 bv = *(const float4*)&row[w0 + 4];
            const float2 cv = *(const float2*)&row[w0 + 8];
            float p = a.x + a.y + a.z + a.w + bv.x + bv.y + bv.z;
            hs[dd][0] = p;
            p += bv.w - a.x; hs[dd][1] = p;
            p += cv.x - a.y; hs[dd][2] = p;
            p += cv.y - a.z; hs[dd][3] = p;
        }
        float* H = Hws + (size_t)(b * HH + y) * FWD;
        #pragma unroll
        for (int xv = 0; xv < 4; ++xv) {
            float4 v0 = {hs[0][xv], hs[1][xv], hs[2][xv],  hs[3][xv]};
            float4 v1 = {hs[4][xv], hs[5][xv], hs[6][xv],  hs[7][xv]};
            float4 v2 = {hs[8][xv], hs[9][xv], hs[10][xv], hs[11][xv]};
            float* p = &H[(w0 + xv) * CW + d0];
            *(float4*)&p[0] = v0;
            *(float4*)&p[4] = v1;
            *(float4*)&p[8] = v2;
        }
    }
}

// ------------- Kernel B: vertical 7-tap running sum, fully coalesced -------------
__global__ __launch_bounds__(256) void vbox(
    const float* __restrict__ Hws, float* __restrict__ out)
{
    const int bid = blockIdx.x;               // grid: b * (HH/HSEG) * 48
    const int fb  = bid % CW;
    const int hs  = (bid / CW) % (HH / HSEG);
    const int b   = bid / (CW * (HH / HSEG));
    const int f   = fb * 256 + threadIdx.x;   // f = w*48 + d
    const int h0  = hs * HSEG;

    const float* H = Hws + (size_t)b * HH * FWD + f;
    float*       O = out + (size_t)b * HH * FWD + f;

    float s = 0.f;
    #pragma unroll
    for (int k = 0; k < 6; ++k) {             // yy = h0-3 .. h0+2
        int yy = h0 - 3 + k;
        if (yy >= 0) s += H[(size_t)yy * FWD];
    }
    #pragma unroll
    for (int hi = 0; hi < HSEG; ++hi) {
        int h = h0 + hi;
        if (h + 3 < HH) s += H[(size_t)(h + 3) * FWD];
        O[(size_t)h * FWD] = s;
        if (h - 3 >= 0) s -= H[(size_t)(h - 3) * FWD];
    }
}

extern "C" void kernel_launch(void* const* d_in, const int* in_sizes, int n_in,
                              void* d_out, int out_size, void* d_ws, size_t ws_size,
                              hipStream_t stream) {
    const float* L = (const float*)d_in[0];
    const float* R = (const float*)d_in[1];
    float* outp = (float*)d_out;
    float* Hws  = (float*)d_ws;   // BB*HH*WW*CW*4 = 12.6 MB

    ssd_hraw<<<dim3(BB * HH), 256, 0, stream>>>(L, R, Hws);
    vbox<<<dim3(BB * (HH / HSEG) * CW), 256, 0, stream>>>(Hws, outp);
}

// Round 7
// 29.106 us; speedup vs baseline: 3.1762x; 1.0200x over previous
//
#include <hip/hip_runtime.h>

#define CW 48
#define HR 3
#define VR 3
#define BB 2
#define CC 16
#define HH 128
#define WW 256

#define LW 312      // Lsh stride: idx = x+3; max read idx 308
#define RW2 264     // Rsh stride: idx = x+3, valid data 3..258
#define SW 264      // Ssh stride: xi 0..261 written, 0..261 read
#define FWD (WW*CW) // 12288 floats per (b,h) plane
#define HSEG 16

// ------------- Kernel A: one block per (b,y) row; 512 threads (8 waves) -------------
// Hws[b][y][w][d] = horizontal 7-tap of ssd_raw(y, x, d), via ssd = el+er-2cc
__global__ __launch_bounds__(512) void ssd_hraw(
    const float* __restrict__ Lg, const float* __restrict__ Rg,
    float* __restrict__ Hws)
{
    const int bid = blockIdx.x;     // 0..255
    const int y   = bid % HH;
    const int b   = bid / HH;
    const int tid = threadIdx.x;

    __shared__ float Lsh[CC * LW];
    __shared__ float Rsh[CC * RW2];
    __shared__ float Ssh[CW * SW];
    __shared__ float el[LW];
    __shared__ float er[RW2];

    // ---- zero pad regions (valid cols overwritten below) ----
    for (int i = tid; i < CC * 56; i += 512) {      // Lsh idx 0..2, 259..311
        int c = i / 56, j = i % 56;
        int idx = (j < 3) ? j : (256 + j);
        Lsh[c * LW + idx] = 0.f;
    }
    for (int i = tid; i < CC * 8; i += 512) {       // Rsh idx 0..2, 259..263
        int c = i >> 3, j = i & 7;
        int idx = (j < 3) ? j : (256 + j);
        Rsh[c * RW2 + idx] = 0.f;
    }
    if (tid < 56) { int idx = (tid < 3) ? tid : (256 + tid); el[idx] = 0.f; }
    else if (tid < 64) { int j = tid - 56; int idx = (j < 3) ? j : (256 + j); er[idx] = 0.f; }

    // ---- stage: waves 0-3 load L column, waves 4-7 load R column; el/er in regs ----
    {
        const int img = tid >> 8;          // 0 = L, 1 = R
        const int col = tid & 255;
        const float* __restrict__ base =
            (img ? Rg : Lg) + ((size_t)b * CC) * (HH * WW) + (size_t)y * WW + col;
        float* sh = (img ? &Rsh[HR + col] : &Lsh[HR + col]);
        const int stride = img ? RW2 : LW;
        float e = 0.f;
        #pragma unroll
        for (int c = 0; c < CC; ++c) {
            float v = base[(size_t)c * (HH * WW)];
            sh[c * stride] = v;
            e = fmaf(v, v, e);
        }
        (img ? er : el)[HR + col] = e;
    }
    __syncthreads();

    // ---- cc partials: every thread does 8 channels for its (q, xi0) unit ----
    const int chalf = tid >> 8;            // 0: c 0..7, 1: c 8..15
    const int unit  = tid & 255;
    const int q     = unit >> 6;           // d0 = 12q
    const int xi0   = (unit & 63) * 4;     // 0..252
    const int d0    = q * 12;

    float acc[12][4];
    #pragma unroll
    for (int dd = 0; dd < 12; ++dd)
        #pragma unroll
        for (int xv = 0; xv < 4; ++xv) acc[dd][xv] = 0.f;

    {
        const int c0 = chalf * 8;
        #pragma unroll
        for (int ci = 0; ci < 8; ++ci) {
            const int c = c0 + ci;
            const float4 rv = *(const float4*)&Rsh[c * RW2 + xi0];
            const float rr[4] = {rv.x, rv.y, rv.z, rv.w};
            float lv[16];
            #pragma unroll
            for (int k = 0; k < 4; ++k)
                *(float4*)&lv[4 * k] = *(const float4*)&Lsh[c * LW + xi0 + d0 + 4 * k];
            #pragma unroll
            for (int dd = 0; dd < 12; ++dd)
                #pragma unroll
                for (int xv = 0; xv < 4; ++xv)
                    acc[dd][xv] = fmaf(lv[dd + xv], rr[xv], acc[dd][xv]);
        }
    }

    if (chalf == 0) {
        // write o = el + er - 2*acc  (chalf-1's -2*acc merged after barrier)
        float elv[16];
        #pragma unroll
        for (int k = 0; k < 4; ++k)
            *(float4*)&elv[4 * k] = *(const float4*)&el[xi0 + d0 + 4 * k];
        const float4 e4 = *(const float4*)&er[xi0];
        const float err4[4] = {e4.x, e4.y, e4.z, e4.w};
        #pragma unroll
        for (int dd = 0; dd < 12; ++dd) {
            float4 o;
            o.x = elv[dd + 0] + err4[0] - 2.f * acc[dd][0];
            o.y = elv[dd + 1] + err4[1] - 2.f * acc[dd][1];
            o.z = elv[dd + 2] + err4[2] - 2.f * acc[dd][2];
            o.w = elv[dd + 3] + err4[3] - 2.f * acc[dd][3];
            *(float4*)&Ssh[(d0 + dd) * SW + xi0] = o;
        }
    } else {
        // leftover xi 256..261 (288 values), full 16 channels, final value
        for (int p = tid - 256; p < 6 * CW; p += 256) {
            int dd = p % CW;
            int xi = 256 + p / CW;
            float a = 0.f;
            #pragma unroll
            for (int c = 0; c < CC; ++c)
                a = fmaf(Lsh[c * LW + xi + dd], Rsh[c * RW2 + xi], a);
            Ssh[dd * SW + xi] = el[xi + dd] + er[xi] - 2.f * a;
        }
    }
    __syncthreads();

    if (chalf == 1) {
        // merge second channel-half: Ssh -= 2*acc
        #pragma unroll
        for (int dd = 0; dd < 12; ++dd) {
            float4 v = *(const float4*)&Ssh[(d0 + dd) * SW + xi0];
            v.x = fmaf(-2.f, acc[dd][0], v.x);
            v.y = fmaf(-2.f, acc[dd][1], v.y);
            v.z = fmaf(-2.f, acc[dd][2], v.z);
            v.w = fmaf(-2.f, acc[dd][3], v.w);
            *(float4*)&Ssh[(d0 + dd) * SW + xi0] = v;
        }
    }
    __syncthreads();

    // ---- horizontal 7-tap, 512 threads: (qh = d-quarter, 2 w per thread) ----
    {
        const int j   = tid & 127;         // w0 = 2j
        const int qh  = tid >> 7;
        const int w0  = 2 * j;
        const int dh0 = qh * 12;
        float hs[12][2];
        #pragma unroll
        for (int dd = 0; dd < 12; ++dd) {
            const float* row = &Ssh[(dh0 + dd) * SW + w0];
            const float2 r0 = *(const float2*)&row[0];
            const float2 r1 = *(const float2*)&row[2];
            const float2 r2 = *(const float2*)&row[4];
            const float2 r3 = *(const float2*)&row[6];
            float h0 = r0.x + r0.y + r1.x + r1.y + r2.x + r2.y + r3.x;
            hs[dd][0] = h0;
            hs[dd][1] = h0 - r0.x + r3.y;
        }
        float* H = Hws + (size_t)(b * HH + y) * FWD;
        #pragma unroll
        for (int xv = 0; xv < 2; ++xv) {
            float4 v0 = {hs[0][xv], hs[1][xv], hs[2][xv],  hs[3][xv]};
            float4 v1 = {hs[4][xv], hs[5][xv], hs[6][xv],  hs[7][xv]};
            float4 v2 = {hs[8][xv], hs[9][xv], hs[10][xv], hs[11][xv]};
            float* p = &H[(w0 + xv) * CW + dh0];
            *(float4*)&p[0] = v0;
            *(float4*)&p[4] = v1;
            *(float4*)&p[8] = v2;
        }
    }
}

// ------------- Kernel B: vertical 7-tap running sum, fully coalesced -------------
__global__ __launch_bounds__(256) void vbox(
    const float* __restrict__ Hws, float* __restrict__ out)
{
    const int bid = blockIdx.x;               // grid: b * (HH/HSEG) * 48
    const int fb  = bid % CW;
    const int hs  = (bid / CW) % (HH / HSEG);
    const int b   = bid / (CW * (HH / HSEG));
    const int f   = fb * 256 + threadIdx.x;   // f = w*48 + d
    const int h0  = hs * HSEG;

    const float* H = Hws + (size_t)b * HH * FWD + f;
    float*       O = out + (size_t)b * HH * FWD + f;

    float s = 0.f;
    #pragma unroll
    for (int k = 0; k < 6; ++k) {             // yy = h0-3 .. h0+2
        int yy = h0 - 3 + k;
        if (yy >= 0) s += H[(size_t)yy * FWD];
    }
    #pragma unroll
    for (int hi = 0; hi < HSEG; ++hi) {
        int h = h0 + hi;
        if (h + 3 < HH) s += H[(size_t)(h + 3) * FWD];
        O[(size_t)h * FWD] = s;
        if (h - 3 >= 0) s -= H[(size_t)(h - 3) * FWD];
    }
}

extern "C" void kernel_launch(void* const* d_in, const int* in_sizes, int n_in,
                              void* d_out, int out_size, void* d_ws, size_t ws_size,
                              hipStream_t stream) {
    const float* L = (const float*)d_in[0];
    const float* R = (const float*)d_in[1];
    float* outp = (float*)d_out;
    float* Hws  = (float*)d_ws;   // BB*HH*WW*CW*4 = 12.6 MB

    ssd_hraw<<<dim3(BB * HH), 512, 0, stream>>>(L, R, Hws);
    vbox<<<dim3(BB * (HH / HSEG) * CW), 256, 0, stream>>>(Hws, outp);
}

// Round 8
// 21.399 us; speedup vs baseline: 4.3203x; 1.3602x over previous
//
#include <hip/hip_runtime.h>
#include <stdint.h>

#define CW 48
#define HR 3
#define VR 3
#define BB 2
#define CC 16
#define HH 128
#define WW 256

#define LW 312      // Lsh stride: idx = x+3; max read idx 308
#define RW2 264     // Rsh stride: idx = x+3, valid data 3..258
#define SW 264      // Ssh stride: xi 0..261 used
#define FWD (WW*CW) // 12288 elements per (b,h) plane
#define HSEG 8

__device__ __forceinline__ uint32_t bf16rn(float f) {
    uint32_t x = __builtin_bit_cast(uint32_t, f);
    uint32_t lsb = (x >> 16) & 1u;
    x += 0x7fffu + lsb;
    return x >> 16;
}

// ------------- Kernel A: one block per (b,y) row; 512 threads (8 waves) -------------
// Hws[b][y][w][d] (bf16) = horizontal 7-tap of ssd_raw(y, x, d), via ssd = el+er-2cc
__global__ __launch_bounds__(512) void ssd_hraw(
    const float* __restrict__ Lg, const float* __restrict__ Rg,
    uint16_t* __restrict__ Hws)
{
    const int bid = blockIdx.x;     // 0..255
    const int y   = bid % HH;
    const int b   = bid / HH;
    const int tid = threadIdx.x;

    __shared__ float Lsh[CC * LW];
    __shared__ float Rsh[CC * RW2];
    __shared__ float Ssh[CW * SW];
    __shared__ float el[LW];
    __shared__ float er[RW2];

    // ---- zero pad regions (valid cols overwritten below) ----
    for (int i = tid; i < CC * 56; i += 512) {      // Lsh idx 0..2, 259..311
        int c = i / 56, j = i % 56;
        int idx = (j < 3) ? j : (256 + j);
        Lsh[c * LW + idx] = 0.f;
    }
    for (int i = tid; i < CC * 8; i += 512) {       // Rsh idx 0..2, 259..263
        int c = i >> 3, j = i & 7;
        int idx = (j < 3) ? j : (256 + j);
        Rsh[c * RW2 + idx] = 0.f;
    }
    if (tid < 56) { int idx = (tid < 3) ? tid : (256 + tid); el[idx] = 0.f; }
    else if (tid < 64) { int j = tid - 56; int idx = (j < 3) ? j : (256 + j); er[idx] = 0.f; }

    // ---- stage: waves 0-3 load L column, waves 4-7 load R column; el/er in regs ----
    {
        const int img = tid >> 8;          // 0 = L, 1 = R
        const int col = tid & 255;
        const float* __restrict__ base =
            (img ? Rg : Lg) + ((size_t)b * CC) * (HH * WW) + (size_t)y * WW + col;
        float* sh = (img ? &Rsh[HR + col] : &Lsh[HR + col]);
        const int stride = img ? RW2 : LW;
        float e = 0.f;
        #pragma unroll
        for (int c = 0; c < CC; ++c) {
            float v = base[(size_t)c * (HH * WW)];
            sh[c * stride] = v;
            e = fmaf(v, v, e);
        }
        (img ? er : el)[HR + col] = e;
    }
    __syncthreads();

    // ---- cc partials: every thread does 8 channels for its (q, xi0) unit ----
    const int chalf = tid >> 8;            // 0: c 0..7, 1: c 8..15
    const int unit  = tid & 255;
    const int q     = unit >> 6;           // d0 = 12q
    const int xi0   = (unit & 63) * 4;     // 0..252
    const int d0    = q * 12;

    float acc[12][4];
    #pragma unroll
    for (int dd = 0; dd < 12; ++dd)
        #pragma unroll
        for (int xv = 0; xv < 4; ++xv) acc[dd][xv] = 0.f;

    {
        const int c0 = chalf * 8;
        #pragma unroll
        for (int ci = 0; ci < 8; ++ci) {
            const int c = c0 + ci;
            const float4 rv = *(const float4*)&Rsh[c * RW2 + xi0];
            const float rr[4] = {rv.x, rv.y, rv.z, rv.w};
            float lv[16];
            #pragma unroll
            for (int k = 0; k < 4; ++k)
                *(float4*)&lv[4 * k] = *(const float4*)&Lsh[c * LW + xi0 + d0 + 4 * k];
            #pragma unroll
            for (int dd = 0; dd < 12; ++dd)
                #pragma unroll
                for (int xv = 0; xv < 4; ++xv)
                    acc[dd][xv] = fmaf(lv[dd + xv], rr[xv], acc[dd][xv]);
        }
    }

    if (chalf == 0) {
        float elv[16];
        #pragma unroll
        for (int k = 0; k < 4; ++k)
            *(float4*)&elv[4 * k] = *(const float4*)&el[xi0 + d0 + 4 * k];
        const float4 e4 = *(const float4*)&er[xi0];
        const float err4[4] = {e4.x, e4.y, e4.z, e4.w};
        #pragma unroll
        for (int dd = 0; dd < 12; ++dd) {
            float4 o;
            o.x = elv[dd + 0] + err4[0] - 2.f * acc[dd][0];
            o.y = elv[dd + 1] + err4[1] - 2.f * acc[dd][1];
            o.z = elv[dd + 2] + err4[2] - 2.f * acc[dd][2];
            o.w = elv[dd + 3] + err4[3] - 2.f * acc[dd][3];
            *(float4*)&Ssh[(d0 + dd) * SW + xi0] = o;
        }
    } else {
        // leftover xi 256..261 (288 values), full 16 channels, final value
        for (int p = tid - 256; p < 6 * CW; p += 256) {
            int dd = p % CW;
            int xi = 256 + p / CW;
            float a = 0.f;
            #pragma unroll
            for (int c = 0; c < CC; ++c)
                a = fmaf(Lsh[c * LW + xi + dd], Rsh[c * RW2 + xi], a);
            Ssh[dd * SW + xi] = el[xi + dd] + er[xi] - 2.f * a;
        }
    }
    __syncthreads();

    if (chalf == 1) {
        // merge second channel-half: Ssh -= 2*acc
        #pragma unroll
        for (int dd = 0; dd < 12; ++dd) {
            float4 v = *(const float4*)&Ssh[(d0 + dd) * SW + xi0];
            v.x = fmaf(-2.f, acc[dd][0], v.x);
            v.y = fmaf(-2.f, acc[dd][1], v.y);
            v.z = fmaf(-2.f, acc[dd][2], v.z);
            v.w = fmaf(-2.f, acc[dd][3], v.w);
            *(float4*)&Ssh[(d0 + dd) * SW + xi0] = v;
        }
    }
    __syncthreads();

    // ---- horizontal 7-tap, 512 threads: (qh = d-quarter, 2 w per thread), bf16 store ----
    {
        const int j   = tid & 127;         // w0 = 2j
        const int qh  = tid >> 7;
        const int w0  = 2 * j;
        const int dh0 = qh * 12;
        float hs[12][2];
        #pragma unroll
        for (int dd = 0; dd < 12; ++dd) {
            const float* row = &Ssh[(dh0 + dd) * SW + w0];
            const float2 r0 = *(const float2*)&row[0];
            const float2 r1 = *(const float2*)&row[2];
            const float2 r2 = *(const float2*)&row[4];
            const float2 r3 = *(const float2*)&row[6];
            float h0 = r0.x + r0.y + r1.x + r1.y + r2.x + r2.y + r3.x;
            hs[dd][0] = h0;
            hs[dd][1] = h0 - r0.x + r3.y;
        }
        uint16_t* H = Hws + (size_t)(b * HH + y) * FWD;
        #pragma unroll
        for (int xv = 0; xv < 2; ++xv) {
            uint32_t pk[6];
            #pragma unroll
            for (int i = 0; i < 6; ++i)
                pk[i] = bf16rn(hs[2 * i][xv]) | (bf16rn(hs[2 * i + 1][xv]) << 16);
            uint32_t* p = (uint32_t*)(H + (size_t)(w0 + xv) * CW + dh0);  // 8B-aligned
            *(uint2*)&p[0] = make_uint2(pk[0], pk[1]);
            *(uint2*)&p[2] = make_uint2(pk[2], pk[3]);
            *(uint2*)&p[4] = make_uint2(pk[4], pk[5]);
        }
    }
}

// ------------- Kernel B: vertical 7-tap over bf16 Hws, fp32 out, fully coalesced -------------
// thread owns one short2-column (two consecutive f = w*48+d slots); HSEG=8 rows
__global__ __launch_bounds__(256) void vbox(
    const uint16_t* __restrict__ Hws, float* __restrict__ out)
{
    const int bid = blockIdx.x;               // grid: BB * (HH/HSEG) * 24
    const int g   = bid % 24;
    const int hs  = (bid / 24) % (HH / HSEG);
    const int b   = bid / (24 * (HH / HSEG));
    const int f2  = g * 256 + threadIdx.x;    // short2-column, 0..6143
    const int h0  = hs * HSEG;

    const uint16_t* H = Hws + (size_t)b * HH * FWD + 2 * f2;
    float*          O = out + (size_t)b * HH * FWD + 2 * f2;

    float vlo[HSEG + 6], vhi[HSEG + 6];
    if (h0 >= 3 && h0 + HSEG + 2 < HH) {
        #pragma unroll
        for (int k = 0; k < HSEG + 6; ++k) {
            uint32_t u = *(const uint32_t*)&H[(size_t)(h0 - 3 + k) * FWD];
            vlo[k] = __builtin_bit_cast(float, u << 16);
            vhi[k] = __builtin_bit_cast(float, u & 0xffff0000u);
        }
    } else {
        #pragma unroll
        for (int k = 0; k < HSEG + 6; ++k) {
            int yy = h0 - 3 + k;
            if (yy >= 0 && yy < HH) {
                uint32_t u = *(const uint32_t*)&H[(size_t)yy * FWD];
                vlo[k] = __builtin_bit_cast(float, u << 16);
                vhi[k] = __builtin_bit_cast(float, u & 0xffff0000u);
            } else { vlo[k] = 0.f; vhi[k] = 0.f; }
        }
    }
    #pragma unroll
    for (int hi = 0; hi < HSEG; ++hi) {
        float slo = vlo[hi], shi = vhi[hi];
        #pragma unroll
        for (int k = 1; k < 7; ++k) { slo += vlo[hi + k]; shi += vhi[hi + k]; }
        *(float2*)&O[(size_t)(h0 + hi) * FWD] = make_float2(slo, shi);
    }
}

extern "C" void kernel_launch(void* const* d_in, const int* in_sizes, int n_in,
                              void* d_out, int out_size, void* d_ws, size_t ws_size,
                              hipStream_t stream) {
    const float* L = (const float*)d_in[0];
    const float* R = (const float*)d_in[1];
    float* outp = (float*)d_out;
    uint16_t* Hws = (uint16_t*)d_ws;   // BB*HH*WW*CW*2 = 6.3 MB

    ssd_hraw<<<dim3(BB * HH), 512, 0, stream>>>(L, R, Hws);
    vbox<<<dim3(BB * (HH / HSEG) * 24), 256, 0, stream>>>(Hws, outp);
}